// Round 4
// baseline (104.520 us; speedup 1.0000x reference)
//
#include <hip/hip_runtime.h>
#include <math.h>

#define NB 4
#define NN 256
#define MAT (NN*NN)      // 65536
#define BMAT (NB*MAT)    // 262144
#define ALPHA 0.2f

typedef __attribute__((ext_vector_type(8))) __bf16 bf16x8;
typedef __attribute__((ext_vector_type(4))) float f32x4;

union U8 { bf16x8 v; unsigned short u[8]; };

__device__ __forceinline__ unsigned short f2bf(float x) {
    unsigned u = __float_as_uint(x);
    u = (u + 0x7FFFu + ((u >> 16) & 1u)) >> 16;
    return (unsigned short)u;
}
__device__ __forceinline__ float bf2f(unsigned short h) {
    return __uint_as_float(((unsigned)h) << 16);
}
__device__ __forceinline__ void split3(float x, unsigned short& a,
                                       unsigned short& b, unsigned short& c) {
    a = f2bf(x); float r = x - bf2f(a);
    b = f2bf(r); r -= bf2f(b);
    c = f2bf(r);
}

__device__ __forceinline__ float wave_sum(float v) {
#pragma unroll
    for (int o = 32; o > 0; o >>= 1) v += __shfl_down(v, o, 64);
    return v;
}
__device__ __forceinline__ float wave_max(float v) {
#pragma unroll
    for (int o = 32; o > 0; o >>= 1) v = fmaxf(v, __shfl_down(v, o, 64));
    return v;
}
__device__ __forceinline__ float block_sum256(float v, volatile float* red) {
    int lane = threadIdx.x & 63, w = threadIdx.x >> 6;
    v = wave_sum(v);
    __syncthreads();
    if (lane == 0) red[w] = v;
    __syncthreads();
    return red[0] + red[1] + red[2] + red[3];
}
__device__ __forceinline__ float block_max256(float v, volatile float* red) {
    int lane = threadIdx.x & 63, w = threadIdx.x >> 6;
    v = wave_max(v);
    __syncthreads();
    if (lane == 0) red[w] = v;
    __syncthreads();
    return fmaxf(fmaxf(red[0], red[1]), fmaxf(red[2], red[3]));
}

// ---- split + transpose the 4 weight matrices into 12 bf16 planes WT[m][p][n][k]
__global__ __launch_bounds__(256) void k_split_w(
    const float* __restrict__ w0, const float* __restrict__ w1,
    const float* __restrict__ w2, const float* __restrict__ w3,
    unsigned short* __restrict__ WT)
{
    int m = blockIdx.y, k = blockIdx.x, j = threadIdx.x;
    const float* Wm = (m == 0) ? w0 : (m == 1) ? w1 : (m == 2) ? w2 : w3;
    float x = Wm[k * NN + j];
    unsigned short s0, s1, s2; split3(x, s0, s1, s2);
    unsigned short* base = WT + m * 3 * MAT;
    base[0 * MAT + j * NN + k] = s0;
    base[1 * MAT + j * NN + k] = s1;
    base[2 * MAT + j * NN + k] = s2;
}

// ---- G = E@wa+ba, H = E@wp+bp via MFMA; A-side split on the fly from f32 E.
// 512 one-wave blocks: m=bid>>8, b=(bid>>6)&3, tile=(bid&63) -> 32x32 C tile.
__global__ __launch_bounds__(64) void k_gh(
    const float* __restrict__ E,
    const unsigned short* __restrict__ WTa, const float* __restrict__ ba,
    const unsigned short* __restrict__ WTp, const float* __restrict__ bp,
    float* __restrict__ G, float* __restrict__ H)
{
    int job = blockIdx.x;
    int m = job >> 8, b = (job >> 6) & 3, t = job & 63;
    int tm = t >> 3, tn = t & 7;
    const unsigned short* WT = m ? WTp : WTa;
    const float* bias = m ? bp : ba;
    float* C = (m ? H : G) + b * MAT;
    const float* Eb = E + b * MAT;
    int l = threadIdx.x;
    int l15 = l & 15, lk = (l >> 4) * 8;

    f32x4 acc[2][2];
#pragma unroll
    for (int rg = 0; rg < 2; ++rg)
#pragma unroll
        for (int cg = 0; cg < 2; ++cg) acc[rg][cg] = 0.0f;

    for (int k0 = 0; k0 < NN; k0 += 32) {
        int kb = k0 + lk;
        U8 a[3][2];
#pragma unroll
        for (int rg = 0; rg < 2; ++rg) {
            int row = tm * 32 + rg * 16 + l15;
            f32x4 e0 = *(const f32x4*)&Eb[row * NN + kb];
            f32x4 e1 = *(const f32x4*)&Eb[row * NN + kb + 4];
#pragma unroll
            for (int i = 0; i < 4; ++i) {
                split3(e0[i], a[0][rg].u[i], a[1][rg].u[i], a[2][rg].u[i]);
                split3(e1[i], a[0][rg].u[i + 4], a[1][rg].u[i + 4], a[2][rg].u[i + 4]);
            }
        }
        U8 w[3][2];
#pragma unroll
        for (int cg = 0; cg < 2; ++cg) {
            int col = tn * 32 + cg * 16 + l15;
#pragma unroll
            for (int p = 0; p < 3; ++p)
                w[p][cg].v = *(const bf16x8*)&WT[p * MAT + col * NN + kb];
        }
        const int TP[6] = {0, 0, 1, 0, 1, 2}, TQ[6] = {0, 1, 0, 2, 1, 0};
#pragma unroll
        for (int t6 = 0; t6 < 6; ++t6) {
            int p = TP[t6], q = TQ[t6];
#pragma unroll
            for (int rg = 0; rg < 2; ++rg)
#pragma unroll
                for (int cg = 0; cg < 2; ++cg)
                    acc[rg][cg] = __builtin_amdgcn_mfma_f32_16x16x32_bf16(
                        a[p][rg].v, w[q][cg].v, acc[rg][cg], 0, 0, 0);
        }
    }
#pragma unroll
    for (int rg = 0; rg < 2; ++rg)
#pragma unroll
        for (int cg = 0; cg < 2; ++cg) {
            int col = tn * 32 + cg * 16 + l15;
            float bv = bias[col];
#pragma unroll
            for (int r = 0; r < 4; ++r) {
                int row = tm * 32 + rg * 16 + (l >> 4) * 4 + r;
                C[row * NN + col] = acc[rg][cg][r] + bv;
            }
        }
}

// ---- adjacency + cnt + eL split planes + rs. grid (NN, NB) x 256.
__global__ __launch_bounds__(256) void k_prep(
    const float* __restrict__ G, const float* __restrict__ H,
    const float* __restrict__ ae,
    unsigned short* __restrict__ adjb,
    unsigned short* __restrict__ eL0, unsigned short* __restrict__ eL1,
    unsigned short* __restrict__ eL2,
    float* __restrict__ cnt, float* __restrict__ rs)
{
    __shared__ float red[4];
    int b = blockIdx.y, i = blockIdx.x, j = threadIdx.x;
    float S = block_sum256(ae[j] + ae[j + NN], red);
    const float* Gb = G + b * MAT;
    float g1 = Gb[i * NN + j], g2 = Gb[j * NN + i];
    float s = 0.5f * (1.f / (1.f + expf(-g1)) + 1.f / (1.f + expf(-g2)));
    float av = (s > 0.5f) ? 1.f : 0.f;
    int idx = b * MAT + i * NN + j;
    adjb[idx] = f2bf(av);
    float c = block_sum256(av, red);
    if (j == 0) cnt[b * NN + i] = c;
    float h = H[idx];
    float x = S * h;
    float L = (x > 0.f) ? x : ALPHA * x;
    float M = block_max256(L, red);
    float e = expf(L - M);
    unsigned short s0, s1, s2; split3(e, s0, s1, s2);
    eL0[idx] = s0; eL1[idx] = s1; eL2[idx] = s2;
    float hs = block_sum256(h, red);
    if (j == 0) rs[b * NN + i] = hs;
}

// ---- attention GEMMs (D/Num) via MFMA + divide/fallback + symmetrize (+tanh).
// grid (36, NB), 64 threads: one wave per unordered tile pair (ti<=tj).
template<int FINAL>
__global__ __launch_bounds__(64) void k_attn(
    const unsigned short* __restrict__ eL0, const unsigned short* __restrict__ eL1,
    const unsigned short* __restrict__ eL2, const float* __restrict__ H,
    const unsigned short* __restrict__ adjb,
    const float* __restrict__ cnt, const float* __restrict__ rs,
    float* __restrict__ Eo)
{
    __shared__ float T0[32 * 33], T1[32 * 33];
    int b = blockIdx.y;
    int ti = 0, rem = blockIdx.x;
    while (rem >= 8 - ti) { rem -= 8 - ti; ++ti; }
    int tj = ti + rem;
    int l = threadIdx.x, l15 = l & 15, lk4 = (l >> 4);

    f32x4 aD[2][2][2], aN[2][2][2];   // [side][rg][cg]
#pragma unroll
    for (int sd = 0; sd < 2; ++sd)
#pragma unroll
        for (int rg = 0; rg < 2; ++rg)
#pragma unroll
            for (int cg = 0; cg < 2; ++cg) { aD[sd][rg][cg] = 0.0f; aN[sd][rg][cg] = 0.0f; }

    for (int j0 = 0; j0 < NN; j0 += 32) {
        int kv = j0 + lk4 * 8;
        U8 Lf[2][3][2], Hf[2][3][2], Af[2][2];
#pragma unroll
        for (int sd = 0; sd < 2; ++sd) {
            int rbase = (sd ? tj : ti) * 32;
#pragma unroll
            for (int rg = 0; rg < 2; ++rg) {
                int row = rbase + rg * 16 + l15;
                int idx = b * MAT + row * NN + kv;
                U8 p0, p1, p2;
                p0.v = *(const bf16x8*)&eL0[idx];
                p1.v = *(const bf16x8*)&eL1[idx];
                p2.v = *(const bf16x8*)&eL2[idx];
                f32x4 h0 = *(const f32x4*)&H[idx];
                f32x4 h1 = *(const f32x4*)&H[idx + 4];
                Lf[sd][0][rg] = p0; Lf[sd][1][rg] = p1; Lf[sd][2][rg] = p2;
#pragma unroll
                for (int iq = 0; iq < 4; ++iq) {
                    float e  = bf2f(p0.u[iq]) + bf2f(p1.u[iq]) + bf2f(p2.u[iq]);
                    float e2 = bf2f(p0.u[iq + 4]) + bf2f(p1.u[iq + 4]) + bf2f(p2.u[iq + 4]);
                    split3(e * h0[iq],  Hf[sd][0][rg].u[iq],     Hf[sd][1][rg].u[iq],     Hf[sd][2][rg].u[iq]);
                    split3(e2 * h1[iq], Hf[sd][0][rg].u[iq + 4], Hf[sd][1][rg].u[iq + 4], Hf[sd][2][rg].u[iq + 4]);
                }
            }
            int cbase = (sd ? ti : tj) * 32;
#pragma unroll
            for (int cg = 0; cg < 2; ++cg) {
                int coln = cbase + cg * 16 + l15;
                Af[sd][cg].v = *(const bf16x8*)&adjb[b * MAT + coln * NN + kv];  // adj symmetric
            }
        }
#pragma unroll
        for (int p = 0; p < 3; ++p)
#pragma unroll
            for (int sd = 0; sd < 2; ++sd)
#pragma unroll
                for (int rg = 0; rg < 2; ++rg)
#pragma unroll
                    for (int cg = 0; cg < 2; ++cg) {
                        aD[sd][rg][cg] = __builtin_amdgcn_mfma_f32_16x16x32_bf16(
                            Lf[sd][p][rg].v, Af[sd][cg].v, aD[sd][rg][cg], 0, 0, 0);
                        aN[sd][rg][cg] = __builtin_amdgcn_mfma_f32_16x16x32_bf16(
                            Hf[sd][p][rg].v, Af[sd][cg].v, aN[sd][rg][cg], 0, 0, 0);
                    }
    }

    const float* cb = cnt + b * NN;
    const float* rb_ = rs + b * NN;
    float Fa[2][2][4], Fb[2][2][4];
#pragma unroll
    for (int cg = 0; cg < 2; ++cg) {
        float cA = cb[tj * 32 + cg * 16 + l15];
        float cB = cb[ti * 32 + cg * 16 + l15];
#pragma unroll
        for (int rg = 0; rg < 2; ++rg)
#pragma unroll
            for (int r = 0; r < 4; ++r) {
                int rA = ti * 32 + rg * 16 + lk4 * 4 + r;
                int rB = tj * 32 + rg * 16 + lk4 * 4 + r;
                Fa[rg][cg][r] = (cA > 0.5f) ? aN[0][rg][cg][r] / aD[0][rg][cg][r]
                                            : rb_[rA] * (1.f / 256.f);
                Fb[rg][cg][r] = (cB > 0.5f) ? aN[1][rg][cg][r] / aD[1][rg][cg][r]
                                            : rb_[rB] * (1.f / 256.f);
            }
    }
#pragma unroll
    for (int rg = 0; rg < 2; ++rg)
#pragma unroll
        for (int cg = 0; cg < 2; ++cg)
#pragma unroll
            for (int r = 0; r < 4; ++r) {
                int R = rg * 16 + lk4 * 4 + r, Cc = cg * 16 + l15;
                T0[R * 33 + Cc] = Fb[rg][cg][r];
                T1[R * 33 + Cc] = Fa[rg][cg][r];
            }
    __syncthreads();
#pragma unroll
    for (int rg = 0; rg < 2; ++rg)
#pragma unroll
        for (int cg = 0; cg < 2; ++cg)
#pragma unroll
            for (int r = 0; r < 4; ++r) {
                int R = rg * 16 + lk4 * 4 + r, Cc = cg * 16 + l15;
                float ea = 0.5f * (Fa[rg][cg][r] + T0[Cc * 33 + R]);
                float eb = 0.5f * (Fb[rg][cg][r] + T1[Cc * 33 + R]);
                int idxA = b * MAT + (ti * 32 + R) * NN + tj * 32 + Cc;
                int idxB = b * MAT + (tj * 32 + R) * NN + ti * 32 + Cc;
                if (FINAL) {
                    float ta = tanhf(ea);
                    Eo[idxA] = ta; Eo[BMAT + idxA] = ta;
                    if (ti != tj) {
                        float tb = tanhf(eb);
                        Eo[idxB] = tb; Eo[BMAT + idxB] = tb;
                    }
                } else {
                    Eo[idxA] = ea;
                    if (ti != tj) Eo[idxB] = eb;
                }
            }
}

extern "C" void kernel_launch(void* const* d_in, const int* in_sizes, int n_in,
                              void* d_out, int out_size, void* d_ws, size_t ws_size,
                              hipStream_t stream) {
    const float* edges = (const float*)d_in[1];
    const float* wp[2] = {(const float*)d_in[7],  (const float*)d_in[17]};
    const float* bp[2] = {(const float*)d_in[8],  (const float*)d_in[18]};
    const float* ae[2] = {(const float*)d_in[9],  (const float*)d_in[19]};
    const float* wa[2] = {(const float*)d_in[10], (const float*)d_in[20]};
    const float* ba[2] = {(const float*)d_in[11], (const float*)d_in[21]};
    float* out = (float*)d_out;

    // ws layout (6.51 MB total; r1-validated budget is >= 7.34 MB)
    unsigned short* WT   = (unsigned short*)d_ws;              // 12 planes * 128KB = 1.5MB
    float* G    = (float*)((char*)d_ws + 12 * MAT * 2);        // 1MB
    float* H    = G + BMAT;                                    // 1MB
    unsigned short* adjb = (unsigned short*)(H + BMAT);        // 0.5MB
    unsigned short* eL0  = adjb + BMAT;                        // 0.5MB
    unsigned short* eL1  = eL0 + BMAT;                         // 0.5MB
    unsigned short* eL2  = eL1 + BMAT;                         // 0.5MB
    float* cnt  = (float*)(eL2 + BMAT);                        // 4KB
    float* rs   = cnt + NB * NN;                               // 4KB
    float* Eslot = rs + NB * NN;                               // 1MB

    // split+transpose all 4 weight matrices (wa0, wp0, wa1, wp1)
    k_split_w<<<dim3(NN, 4), NN, 0, stream>>>(wa[0], wp[0], wa[1], wp[1], WT);

    const float* Ecur = edges;
    for (int l = 0; l < 2; ++l) {
        const unsigned short* WTa = WT + (l * 2 + 0) * 3 * MAT;
        const unsigned short* WTp = WT + (l * 2 + 1) * 3 * MAT;
        k_gh<<<512, 64, 0, stream>>>(Ecur, WTa, ba[l], WTp, bp[l], G, H);
        k_prep<<<dim3(NN, NB), NN, 0, stream>>>(G, H, ae[l], adjb, eL0, eL1, eL2, cnt, rs);
        if (l == 0)
            k_attn<0><<<dim3(36, NB), 64, 0, stream>>>(eL0, eL1, eL2, H, adjb, cnt, rs, Eslot);
        else
            k_attn<1><<<dim3(36, NB), 64, 0, stream>>>(eL0, eL1, eL2, H, adjb, cnt, rs, out);
        Ecur = Eslot;
    }
}

// Round 5
// 69.807 us; speedup vs baseline: 1.4973x; 1.4973x over previous
//
#include <hip/hip_runtime.h>
#include <math.h>

#define NB 4
#define NN 256
#define MAT (NN*NN)      // 65536
#define BMAT (NB*MAT)    // 262144
#define ALPHA 0.2f

typedef __attribute__((ext_vector_type(8))) __bf16 bf16x8;
typedef __attribute__((ext_vector_type(4))) float f32x4;

union U8 { bf16x8 v; unsigned short u[8]; };

__device__ __forceinline__ unsigned short f2bf(float x) {
    unsigned u = __float_as_uint(x);
    u = (u + 0x7FFFu + ((u >> 16) & 1u)) >> 16;
    return (unsigned short)u;
}
__device__ __forceinline__ float bf2f(unsigned short h) {
    return __uint_as_float(((unsigned)h) << 16);
}
__device__ __forceinline__ void split3(float x, unsigned short& a,
                                       unsigned short& b, unsigned short& c) {
    a = f2bf(x); float r = x - bf2f(a);
    b = f2bf(r); r -= bf2f(b);
    c = f2bf(r);
}

__device__ __forceinline__ float wave_sum(float v) {
#pragma unroll
    for (int o = 32; o > 0; o >>= 1) v += __shfl_down(v, o, 64);
    return v;
}
__device__ __forceinline__ float wave_max(float v) {
#pragma unroll
    for (int o = 32; o > 0; o >>= 1) v = fmaxf(v, __shfl_down(v, o, 64));
    return v;
}
__device__ __forceinline__ float block_sum256(float v, volatile float* red) {
    int lane = threadIdx.x & 63, w = threadIdx.x >> 6;
    v = wave_sum(v);
    __syncthreads();
    if (lane == 0) red[w] = v;
    __syncthreads();
    return red[0] + red[1] + red[2] + red[3];
}
__device__ __forceinline__ float block_max256(float v, volatile float* red) {
    int lane = threadIdx.x & 63, w = threadIdx.x >> 6;
    v = wave_max(v);
    __syncthreads();
    if (lane == 0) red[w] = v;
    __syncthreads();
    return fmaxf(fmaxf(red[0], red[1]), fmaxf(red[2], red[3]));
}

// ---- k_pre: 2048 blocks. bid<1024: W split+transpose (4 matrices).
//            bid>=1024: E split into 3 bf16 planes (layer-0 input).
__global__ __launch_bounds__(256) void k_pre(
    const float* __restrict__ w0, const float* __restrict__ w1,
    const float* __restrict__ w2, const float* __restrict__ w3,
    const float* __restrict__ edges,
    unsigned short* __restrict__ WT, unsigned short* __restrict__ Epl)
{
    int bid = blockIdx.x, tid = threadIdx.x;
    if (bid < 1024) {
        int m = bid >> 8, k = bid & 255, j = tid;
        const float* Wm = (m == 0) ? w0 : (m == 1) ? w1 : (m == 2) ? w2 : w3;
        float x = Wm[k * NN + j];
        unsigned short s0, s1, s2; split3(x, s0, s1, s2);
        unsigned short* base = WT + m * 3 * MAT;
        base[0 * MAT + j * NN + k] = s0;
        base[1 * MAT + j * NN + k] = s1;
        base[2 * MAT + j * NN + k] = s2;
    } else {
        int idx = (bid - 1024) * 256 + tid;
        unsigned short s0, s1, s2; split3(edges[idx], s0, s1, s2);
        Epl[idx] = s0; Epl[BMAT + idx] = s1; Epl[2 * BMAT + idx] = s2;
    }
}

// ---- k_gh: G = E@wa+ba, H = E@wp+bp. 1024 one-wave blocks, 16x32 tiles.
// bid: m=bid>>9, b=(bid>>7)&3, t=bid&127 -> tm=t>>3 (16-row), tn=t&7 (32-col)
__global__ __launch_bounds__(64) void k_gh(
    const unsigned short* __restrict__ Epl,
    const unsigned short* __restrict__ WTa, const float* __restrict__ ba,
    const unsigned short* __restrict__ WTp, const float* __restrict__ bp,
    float* __restrict__ G, float* __restrict__ H)
{
    int bid = blockIdx.x;
    int m = bid >> 9, b = (bid >> 7) & 3, t = bid & 127;
    int tm = t >> 3, tn = t & 7;
    const unsigned short* WT = m ? WTp : WTa;
    const float* bias = m ? bp : ba;
    float* C = (m ? H : G) + b * MAT;
    int l = threadIdx.x, l15 = l & 15, lk = (l >> 4) * 8, lk4 = l >> 4;

    f32x4 acc[2]; acc[0] = 0.0f; acc[1] = 0.0f;
    int arow = b * MAT + (tm * 16 + l15) * NN;
    for (int k0 = 0; k0 < NN; k0 += 32) {
        int kb = k0 + lk;
        U8 a[3], w[3][2];
#pragma unroll
        for (int p = 0; p < 3; ++p)
            a[p].v = *(const bf16x8*)&Epl[p * BMAT + arow + kb];
#pragma unroll
        for (int cg = 0; cg < 2; ++cg) {
            int col = tn * 32 + cg * 16 + l15;
#pragma unroll
            for (int p = 0; p < 3; ++p)
                w[p][cg].v = *(const bf16x8*)&WT[p * MAT + col * NN + kb];
        }
        const int TP[6] = {0, 0, 1, 0, 1, 2}, TQ[6] = {0, 1, 0, 2, 1, 0};
#pragma unroll
        for (int t6 = 0; t6 < 6; ++t6)
#pragma unroll
            for (int cg = 0; cg < 2; ++cg)
                acc[cg] = __builtin_amdgcn_mfma_f32_16x16x32_bf16(
                    a[TP[t6]].v, w[TQ[t6]][cg].v, acc[cg], 0, 0, 0);
    }
#pragma unroll
    for (int cg = 0; cg < 2; ++cg) {
        int col = tn * 32 + cg * 16 + l15;
        float bv = bias[col];
#pragma unroll
        for (int r = 0; r < 4; ++r) {
            int row = tm * 16 + lk4 * 4 + r;
            C[row * NN + col] = acc[cg][r] + bv;
        }
    }
}

// ---- k_prep: adjacency + cnt + eL/eH planes + rs. grid (NN, NB) x 256.
__global__ __launch_bounds__(256) void k_prep(
    const float* __restrict__ G, const float* __restrict__ H,
    const float* __restrict__ ae,
    unsigned short* __restrict__ adjb,
    unsigned short* __restrict__ eLp, unsigned short* __restrict__ eHp,
    float* __restrict__ cnt, float* __restrict__ rs)
{
    __shared__ float red[4];
    int b = blockIdx.y, i = blockIdx.x, j = threadIdx.x;
    float S = block_sum256(ae[j] + ae[j + NN], red);
    const float* Gb = G + b * MAT;
    float g1 = Gb[i * NN + j], g2 = Gb[j * NN + i];
    float s = 0.5f * (1.f / (1.f + expf(-g1)) + 1.f / (1.f + expf(-g2)));
    float av = (s > 0.5f) ? 1.f : 0.f;
    int idx = b * MAT + i * NN + j;
    adjb[idx] = f2bf(av);
    float c = block_sum256(av, red);
    if (j == 0) cnt[b * NN + i] = c;
    float h = H[idx];
    float x = S * h;
    float L = (x > 0.f) ? x : ALPHA * x;
    float M = block_max256(L, red);
    float e = expf(L - M);
    unsigned short s0, s1, s2;
    split3(e, s0, s1, s2);
    eLp[idx] = s0; eLp[BMAT + idx] = s1; eLp[2 * BMAT + idx] = s2;
    split3(e * h, s0, s1, s2);
    eHp[idx] = s0; eHp[BMAT + idx] = s1; eHp[2 * BMAT + idx] = s2;
    float hs = block_sum256(h, red);
    if (j == 0) rs[b * NN + i] = hs;
}

// ---- k_F: D/N GEMMs + divide/fallback -> F. 1024 one-wave blocks, 16x16 tiles.
// bid: b=bid>>8, t=bid&255 -> ti=t>>4 (rows), tj=t&15 (cols)
__global__ __launch_bounds__(64) void k_F(
    const unsigned short* __restrict__ eLp, const unsigned short* __restrict__ eHp,
    const unsigned short* __restrict__ adjb,
    const float* __restrict__ cnt, const float* __restrict__ rs,
    float* __restrict__ F)
{
    int bid = blockIdx.x;
    int b = bid >> 8, t = bid & 255;
    int ti = t >> 4, tj = t & 15;
    int l = threadIdx.x, l15 = l & 15, lk = (l >> 4) * 8, lk4 = l >> 4;

    f32x4 aD = 0.0f, aN = 0.0f;
    int arow = b * MAT + (ti * 16 + l15) * NN;
    int brow = b * MAT + (tj * 16 + l15) * NN;
    for (int j0 = 0; j0 < NN; j0 += 32) {
        int kv = j0 + lk;
        U8 Lf[3], Hf[3], Af;
#pragma unroll
        for (int p = 0; p < 3; ++p) {
            Lf[p].v = *(const bf16x8*)&eLp[p * BMAT + arow + kv];
            Hf[p].v = *(const bf16x8*)&eHp[p * BMAT + arow + kv];
        }
        Af.v = *(const bf16x8*)&adjb[brow + kv];
#pragma unroll
        for (int p = 0; p < 3; ++p) {
            aD = __builtin_amdgcn_mfma_f32_16x16x32_bf16(Lf[p].v, Af.v, aD, 0, 0, 0);
            aN = __builtin_amdgcn_mfma_f32_16x16x32_bf16(Hf[p].v, Af.v, aN, 0, 0, 0);
        }
    }
    int col = tj * 16 + l15;
    float cA = cnt[b * NN + col];
#pragma unroll
    for (int r = 0; r < 4; ++r) {
        int row = ti * 16 + lk4 * 4 + r;
        float fv = (cA > 0.5f) ? aN[r] / aD[r] : rs[b * NN + row] * (1.f / 256.f);
        F[b * MAT + row * NN + col] = fv;
    }
}

// ---- k_sym: symmetrize tile pairs (16x16). FINAL=0: emit E planes.
// FINAL=1: tanh + duplicated store to out. grid (136, NB) x 256.
template<int FINAL>
__global__ __launch_bounds__(256) void k_sym(
    const float* __restrict__ F, unsigned short* __restrict__ Epl,
    float* __restrict__ out)
{
    __shared__ float Ta[16 * 17], Tb[16 * 17];
    int b = blockIdx.y;
    int ti = 0, rem = blockIdx.x;
    while (rem >= 16 - ti) { rem -= 16 - ti; ++ti; }
    int tj = ti + rem;
    int tid = threadIdx.x, r = tid >> 4, c = tid & 15;

    int idxA = b * MAT + (ti * 16 + r) * NN + tj * 16 + c;
    int idxB = b * MAT + (tj * 16 + r) * NN + ti * 16 + c;
    float Fa = F[idxA];
    float Fb = F[idxB];
    Ta[r * 17 + c] = Fa;
    Tb[r * 17 + c] = Fb;
    __syncthreads();
    float ea = 0.5f * (Fa + Tb[c * 17 + r]);
    float eb = 0.5f * (Fb + Ta[c * 17 + r]);
    if (FINAL) {
        float ta = tanhf(ea);
        out[idxA] = ta; out[BMAT + idxA] = ta;
        if (ti != tj) {
            float tb = tanhf(eb);
            out[idxB] = tb; out[BMAT + idxB] = tb;
        }
    } else {
        unsigned short s0, s1, s2;
        split3(ea, s0, s1, s2);
        Epl[idxA] = s0; Epl[BMAT + idxA] = s1; Epl[2 * BMAT + idxA] = s2;
        if (ti != tj) {
            split3(eb, s0, s1, s2);
            Epl[idxB] = s0; Epl[BMAT + idxB] = s1; Epl[2 * BMAT + idxB] = s2;
        }
    }
}

extern "C" void kernel_launch(void* const* d_in, const int* in_sizes, int n_in,
                              void* d_out, int out_size, void* d_ws, size_t ws_size,
                              hipStream_t stream) {
    const float* edges = (const float*)d_in[1];
    const float* wp[2] = {(const float*)d_in[7],  (const float*)d_in[17]};
    const float* bp[2] = {(const float*)d_in[8],  (const float*)d_in[18]};
    const float* ae[2] = {(const float*)d_in[9],  (const float*)d_in[19]};
    const float* wa[2] = {(const float*)d_in[10], (const float*)d_in[20]};
    const float* ba[2] = {(const float*)d_in[11], (const float*)d_in[21]};
    float* out = (float*)d_out;

    // ws layout (~11.5 MB of the ~256 MB workspace)
    unsigned short* WT   = (unsigned short*)d_ws;     // 12 planes * 128KB = 1.5MB
    unsigned short* EplA = WT + 12 * MAT;             // 3 * BMAT bf16 = 1.5MB
    unsigned short* EplB = EplA + 3 * BMAT;           // 1.5MB
    unsigned short* adjb = EplB + 3 * BMAT;           // 0.5MB
    unsigned short* eLp  = adjb + BMAT;               // 3 planes = 1.5MB
    unsigned short* eHp  = eLp + 3 * BMAT;            // 3 planes = 1.5MB
    float* G   = (float*)(eHp + 3 * BMAT);            // 1MB
    float* H   = G + BMAT;                            // 1MB
    float* F   = H + BMAT;                            // 1MB
    float* cnt = F + BMAT;                            // 4KB
    float* rs  = cnt + NB * NN;                       // 4KB

    k_pre<<<2048, 256, 0, stream>>>(wa[0], wp[0], wa[1], wp[1], edges, WT, EplA);

    for (int l = 0; l < 2; ++l) {
        const unsigned short* WTa = WT + (l * 2 + 0) * 3 * MAT;
        const unsigned short* WTp = WT + (l * 2 + 1) * 3 * MAT;
        const unsigned short* Ein = l ? EplB : EplA;
        k_gh<<<1024, 64, 0, stream>>>(Ein, WTa, ba[l], WTp, bp[l], G, H);
        k_prep<<<dim3(NN, NB), 256, 0, stream>>>(G, H, ae[l], adjb, eLp, eHp, cnt, rs);
        k_F<<<1024, 64, 0, stream>>>(eLp, eHp, adjb, cnt, rs, F);
        if (l == 0)
            k_sym<0><<<dim3(136, NB), 256, 0, stream>>>(F, EplB, nullptr);
        else
            k_sym<1><<<dim3(136, NB), 256, 0, stream>>>(F, nullptr, out);
    }
}